// Round 6
// baseline (170.754 us; speedup 1.0000x reference)
//
#include <hip/hip_runtime.h>
#include <math.h>

#define BB 4
#define LL 4096
#define DD 256
#define NROWS (BB*LL)      // 16384
#define CHUNK 32
#define NC (LL/CHUNK)      // 128
#define NB 8192            // counting-sort bins

// ---------------- K1: u_q = Wq^T w, u_k = Wk^T w (u pre-zeroed) ----------------
// grid 16 blocks, block g sums e in [16g,16g+16), atomicAdd partials.
__global__ void k_uvec(const float* __restrict__ Wq, const float* __restrict__ Wk,
                       const float* __restrict__ w, float* __restrict__ u) {
    __shared__ float wl[16];
    int d = threadIdx.x;
    int e0 = blockIdx.x * 16;
    if (d < 16) wl[d] = w[e0 + d];
    __syncthreads();
    float aq = 0.f, ak = 0.f;
    #pragma unroll
    for (int j = 0; j < 16; ++j) {
        float we = wl[j];
        aq = fmaf(Wq[(size_t)(e0 + j)*DD + d], we, aq);
        ak = fmaf(Wk[(size_t)(e0 + j)*DD + d], we, ak);
    }
    atomicAdd(&u[d], aq);
    atomicAdd(&u[DD + d], ak);
}

// ---------------- K2: a_i = x_i . u_q + b ; c_i = x_i . u_k ----------------
__global__ void k_proj(const float* __restrict__ x, const float* __restrict__ u,
                       const float* __restrict__ bmlp,
                       float* __restrict__ a, float* __restrict__ c) {
    int row = blockIdx.x * 4 + (threadIdx.x >> 6);
    int lane = threadIdx.x & 63;
    float4 xv = ((const float4*)(x + (size_t)row * DD))[lane];
    float4 uq = ((const float4*)u)[lane];
    float4 uk = ((const float4*)(u + DD))[lane];
    float sq = xv.x*uq.x + xv.y*uq.y + xv.z*uq.z + xv.w*uq.w;
    float sk = xv.x*uk.x + xv.y*uk.y + xv.z*uk.z + xv.w*uk.w;
    #pragma unroll
    for (int off = 32; off > 0; off >>= 1) {
        sq += __shfl_down(sq, off);
        sk += __shfl_down(sk, off);
    }
    if (lane == 0) {
        a[row] = sq + bmlp[0];
        c[row] = sk;
    }
}

// ---------------- K3: counting sort by value-bin + SE prefix ----------------
__global__ void __launch_bounds__(1024) k_sortish(const float* __restrict__ c,
        int* __restrict__ binstart_g,       // [BB][NB+2]
        int* __restrict__ perm,             // [BB][LL]
        float* __restrict__ c_sorted, float* __restrict__ e_sorted,
        float* __restrict__ SE,             // [BB][LL+1]
        float* __restrict__ hdr) {          // [BB][2] = {cmin, scale}
    __shared__ float cl[LL];       // 16 KB
    __shared__ int   hist[NB];     // 32 KB
    __shared__ float esl[LL];      // 16 KB
    __shared__ float scrf[64];
    int b = blockIdx.x, tid = threadIdx.x;
    int wave = tid >> 6, lane = tid & 63;
    int* scri = (int*)scrf;

    // 1. load c, find min/max
    float4 cv = ((const float4*)(c + (size_t)b*LL))[tid];
    ((float4*)cl)[tid] = cv;
    float cw[4] = {cv.x, cv.y, cv.z, cv.w};
    float mn = fminf(fminf(cw[0],cw[1]), fminf(cw[2],cw[3]));
    float mx = fmaxf(fmaxf(cw[0],cw[1]), fmaxf(cw[2],cw[3]));
    #pragma unroll
    for (int off = 32; off > 0; off >>= 1) {
        mn = fminf(mn, __shfl_down(mn, off));
        mx = fmaxf(mx, __shfl_down(mx, off));
    }
    if (lane == 0) { scrf[wave] = mn; scrf[32 + wave] = mx; }
    __syncthreads();
    if (wave == 0) {
        float m = (lane < 16) ? scrf[lane]      :  3.4e38f;
        float M = (lane < 16) ? scrf[32 + lane] : -3.4e38f;
        #pragma unroll
        for (int off = 32; off > 0; off >>= 1) {
            m = fminf(m, __shfl_down(m, off));
            M = fmaxf(M, __shfl_down(M, off));
        }
        if (lane == 0) { scrf[0] = m; scrf[1] = M; }
    }
    __syncthreads();
    float cmin = scrf[0], cmax = scrf[1];
    float scale = (float)NB / fmaxf(cmax - cmin, 1e-20f);
    __syncthreads();

    // 2. zero histogram (int4)
    ((int4*)hist)[tid] = make_int4(0,0,0,0);
    ((int4*)hist)[tid + 1024] = make_int4(0,0,0,0);
    __syncthreads();

    // 3. histogram
    int bins[4];
    #pragma unroll
    for (int u = 0; u < 4; ++u) {
        int bi = (int)((cw[u] - cmin) * scale);
        bi = bi < 0 ? 0 : (bi > NB-1 ? NB-1 : bi);
        bins[u] = bi;
        atomicAdd(&hist[bi], 1);
    }
    __syncthreads();

    // 4. exclusive scan of hist (8 bins/thread, then 1024-thread scan)
    int loc[8]; int base = 0;
    #pragma unroll
    for (int j = 0; j < 8; ++j) { loc[j] = base; base += hist[tid*8 + j]; }
    int incl = base;
    #pragma unroll
    for (int off = 1; off < 64; off <<= 1) {
        int t = __shfl_up(incl, off);
        if (lane >= off) incl += t;
    }
    if (lane == 63) scri[wave] = incl;
    __syncthreads();
    if (wave == 0) {
        int v = (lane < 16) ? scri[lane] : 0;
        int s = v;
        #pragma unroll
        for (int off = 1; off < 16; off <<= 1) {
            int t = __shfl_up(s, off);
            if (lane >= off) s += t;
        }
        if (lane < 16) scri[lane] = s - v;   // exclusive wave offsets
    }
    __syncthreads();
    int thread_excl = (incl - base) + scri[wave];
    __syncthreads();                          // all reads of scri/hist done
    #pragma unroll
    for (int j = 0; j < 8; ++j) {
        int bs = thread_excl + loc[j];
        binstart_g[(size_t)b*(NB+2) + tid*8 + j] = bs;
        hist[tid*8 + j] = bs;                // LDS copy for scatter
    }
    if (tid == 0) {
        binstart_g[(size_t)b*(NB+2) + NB]     = LL;
        binstart_g[(size_t)b*(NB+2) + NB + 1] = LL;
        hdr[b*2 + 0] = cmin;
        hdr[b*2 + 1] = scale;
    }
    __syncthreads();

    // 5. scatter (atomic rank within bin; order-independent at boundaries)
    #pragma unroll
    for (int u = 0; u < 4; ++u) {
        int i = tid*4 + u;
        int r = atomicAdd(&hist[bins[u]], 1);
        float e = expf(cmin - cw[u]);         // <= 1 (cw >= cmin)
        perm[(size_t)b*LL + r] = i;
        c_sorted[(size_t)b*LL + r] = cw[u];
        e_sorted[(size_t)b*LL + r] = e;
        esl[r] = e;
    }
    __syncthreads();

    // 6. exclusive prefix SE over esl
    float le[4]; float s0 = 0.f;
    #pragma unroll
    for (int u = 0; u < 4; ++u) { le[u] = s0; s0 += esl[tid*4 + u]; }
    float fincl = s0;
    #pragma unroll
    for (int off = 1; off < 64; off <<= 1) {
        float t = __shfl_up(fincl, off);
        if (lane >= off) fincl += t;
    }
    if (lane == 63) scrf[wave] = fincl;
    __syncthreads();
    if (wave == 0) {
        float v = (lane < 16) ? scrf[lane] : 0.f;
        float s = v;
        #pragma unroll
        for (int off = 1; off < 16; off <<= 1) {
            float t = __shfl_up(s, off);
            if (lane >= off) s += t;
        }
        if (lane < 16) scrf[lane] = s - v;
    }
    __syncthreads();
    float texcl = (fincl - s0) + scrf[wave];
    #pragma unroll
    for (int u = 0; u < 4; ++u)
        SE[(size_t)b*(LL+1) + tid*4 + u] = texcl + le[u];
    if (tid == 1023) SE[(size_t)b*(LL+1) + LL] = texcl + s0;
}

// ---------------- K4: V = x @ Wv^T ----------------
// 64x128 tile, 128 threads (2 waves), micro 8 rows (ty+8r) x 8 cols (tx+16s).
// Grid = 1024 blocks -> ~4 scheduled/CU (latency hiding via block-level overlap;
// round-5 showed 2 blocks/CU leaves the CU idle during barrier drains).
// LDS 24 KB, XOR-swizzled slot [m][kc ^ (m&7)]:
//   staging writes (8-lane quantum: m fixed, kc 0..7) -> bijection over all 8
//   bank groups; A reads (kc fixed, m=ty+8r, ty 0..3 per wave) -> 4 addrs, 4
//   distinct groups; B reads (n=tx+16s) -> 2 addrs/group = free (m136).
// Single-buffered, no held prefetch regs (round-4 spill lesson).
__global__ void __launch_bounds__(128) k_gemm_v(const float* __restrict__ x,
        const float* __restrict__ Wv, float* __restrict__ V) {
    __shared__ float4 As[64*8];      // 8 KB
    __shared__ float4 Bs[128*8];     // 16 KB
    const int tid = threadIdx.x;
    const int rowBase = blockIdx.x * 64;
    const int colBase = blockIdx.y * 128;
    const int ty = tid >> 4;         // [0,8): rows ty + 8r, r<8
    const int tx = tid & 15;         // [0,16): cols tx + 16s, s<8

    float acc[8][8];
    #pragma unroll
    for (int r = 0; r < 8; ++r)
        #pragma unroll
        for (int s = 0; s < 8; ++s) acc[r][s] = 0.f;

    for (int k0 = 0; k0 < DD; k0 += 32) {
        __syncthreads();
        // stage A: 512 float4 / 128 thr = 4 each
        #pragma unroll
        for (int rep = 0; rep < 4; ++rep) {
            int idx = tid + 128*rep;
            int m = idx >> 3, kc = idx & 7;
            As[m*8 + (kc ^ (m & 7))] =
                *(const float4*)(x + (size_t)(rowBase + m) * DD + k0 + 4*kc);
        }
        // stage B: 1024 float4 / 128 thr = 8 each
        #pragma unroll
        for (int rep = 0; rep < 8; ++rep) {
            int idx = tid + 128*rep;
            int n = idx >> 3, kc = idx & 7;
            Bs[n*8 + (kc ^ (n & 7))] =
                *(const float4*)(Wv + (size_t)(colBase + n) * DD + k0 + 4*kc);
        }
        __syncthreads();
        #pragma unroll
        for (int kc = 0; kc < 8; ++kc) {
            float4 af[8], bf[8];
            #pragma unroll
            for (int r = 0; r < 8; ++r) {
                int m = ty + 8*r;
                af[r] = As[m*8 + (kc ^ (m & 7))];
            }
            #pragma unroll
            for (int s = 0; s < 8; ++s) {
                int n = tx + 16*s;
                bf[s] = Bs[n*8 + (kc ^ (n & 7))];
            }
            #pragma unroll
            for (int r = 0; r < 8; ++r)
                #pragma unroll
                for (int s = 0; s < 8; ++s) {
                    acc[r][s] = fmaf(af[r].x, bf[s].x, acc[r][s]);
                    acc[r][s] = fmaf(af[r].y, bf[s].y, acc[r][s]);
                    acc[r][s] = fmaf(af[r].z, bf[s].z, acc[r][s]);
                    acc[r][s] = fmaf(af[r].w, bf[s].w, acc[r][s]);
                }
        }
    }
    #pragma unroll
    for (int r = 0; r < 8; ++r) {
        size_t rowo = (size_t)(rowBase + ty + 8*r) * DD + colBase;
        #pragma unroll
        for (int s = 0; s < 8; ++s)
            V[rowo + tx + 16*s] = acc[r][s];
    }
}

// ---------------- K5: chunked exclusive prefix over V in rank order ----------------
__global__ void k_scan(const float* __restrict__ V, const int* __restrict__ perm,
        const float* __restrict__ e_sorted,
        float* __restrict__ Pl, float* __restrict__ Pel,
        float* __restrict__ Tp, float* __restrict__ Te) {
    int b = blockIdx.y, q = blockIdx.x;
    int d = threadIdx.x;
    __shared__ int pj[CHUNK];
    __shared__ float pe[CHUNK];
    if (d < CHUNK) {
        pj[d] = perm[(size_t)b*LL + q*CHUNK + d];
        pe[d] = e_sorted[(size_t)b*LL + q*CHUNK + d];
    }
    __syncthreads();
    float vr[CHUNK];
    #pragma unroll
    for (int r = 0; r < CHUNK; ++r)
        vr[r] = V[((size_t)b*LL + pj[r]) * DD + d];
    float acc = 0.f, acce = 0.f;
    size_t kb = (size_t)b*LL + (size_t)q*CHUNK;
    #pragma unroll
    for (int r = 0; r < CHUNK; ++r) {
        size_t o = (kb + r) * DD + d;
        Pl[o]  = acc;
        Pel[o] = acce;
        acc += vr[r];
        acce = fmaf(pe[r], vr[r], acce);
    }
    size_t to = ((size_t)b*NC + q) * DD + d;
    Tp[to] = acc;
    Te[to] = acce;
}

// ---------------- K6: scan chunk totals -> chunk bases (+ grand total) ----------------
__global__ void k_base(const float* __restrict__ Tp, const float* __restrict__ Te,
        float* __restrict__ baseP, float* __restrict__ basePe) {
    int b = blockIdx.x, d = threadIdx.x;
    float acc = 0.f, acce = 0.f;
    #pragma unroll 16
    for (int q = 0; q < NC; ++q) {
        size_t o = ((size_t)b*(NC+1) + q) * DD + d;
        baseP[o] = acc; basePe[o] = acce;
        size_t ti = ((size_t)b*NC + q) * DD + d;
        acc += Tp[ti]; acce += Te[ti];
    }
    size_t o = ((size_t)b*(NC+1) + NC) * DD + d;
    baseP[o] = acc; basePe[o] = acce;
}

// ---------------- K7: per-row output, O(1) bin lookup + exact boundary fix ----------------
__global__ void k_out(const float* __restrict__ a, const float* __restrict__ hdr,
                      const int* __restrict__ binstart,
                      const float* __restrict__ c_sorted, const float* __restrict__ e_sorted,
                      const int* __restrict__ perm, const float* __restrict__ V,
                      const float* __restrict__ SE,
                      const float* __restrict__ Pl, const float* __restrict__ Pel,
                      const float* __restrict__ baseP, const float* __restrict__ basePe,
                      float* __restrict__ out) {
    int row = blockIdx.x * 4 + (threadIdx.x >> 6);
    int lane = threadIdx.x & 63;
    int b = row >> 12;
    float ai = a[row];
    float cmin = hdr[b*2 + 0], scale = hdr[b*2 + 1];
    float t = (ai - cmin) * scale;
    int ib = t < 0.f ? 0 : (t >= (float)NB ? NB : (int)t);
    int k    = binstart[(size_t)b*(NB+2) + ib];
    int kend = binstart[(size_t)b*(NB+2) + ib + 1];
    float alpha = expf(cmin - ai);
    float Z = fmaf(alpha, (float)(LL - k), SE[(size_t)b*(LL+1) + k]);
    size_t db = (size_t)lane * 4;
    size_t totoff = ((size_t)b * (NC+1) + NC) * DD + db;
    float4 ptot  = *(const float4*)(baseP  + totoff);
    float4 pk, pek;
    if (k < LL) {
        int q = k >> 5;
        size_t po = ((size_t)b * LL + k) * DD + db;
        size_t bo = ((size_t)b * (NC+1) + q) * DD + db;
        float4 pl = *(const float4*)(Pl    + po);
        float4 bp = *(const float4*)(baseP + bo);
        float4 pe = *(const float4*)(Pel    + po);
        float4 be = *(const float4*)(basePe + bo);
        pk.x = pl.x + bp.x; pk.y = pl.y + bp.y; pk.z = pl.z + bp.z; pk.w = pl.w + bp.w;
        pek.x = pe.x + be.x; pek.y = pe.y + be.y; pek.z = pe.z + be.z; pek.w = pe.w + be.w;
    } else {
        pk = ptot;
        float4 pt = *(const float4*)(basePe + totoff);
        pek = pt;
    }
    float4 num;
    num.x = fmaf(alpha, ptot.x - pk.x, pek.x);
    num.y = fmaf(alpha, ptot.y - pk.y, pek.y);
    num.z = fmaf(alpha, ptot.z - pk.z, pek.z);
    num.w = fmaf(alpha, ptot.w - pk.w, pek.w);
    // exact correction for keys sharing a_i's bin (expected ~1-3 elements)
    for (int r = k; r < kend; ++r) {
        float cr = c_sorted[(size_t)b*LL + r];
        if (cr < ai) {
            float w = e_sorted[(size_t)b*LL + r] - alpha;
            int j = perm[(size_t)b*LL + r];
            float4 v = *(const float4*)(V + ((size_t)b*LL + j) * DD + db);
            num.x = fmaf(w, v.x, num.x);
            num.y = fmaf(w, v.y, num.y);
            num.z = fmaf(w, v.z, num.z);
            num.w = fmaf(w, v.w, num.w);
            Z += w;
        }
    }
    float invZ = 1.f / Z;
    float4 o;
    o.x = num.x * invZ; o.y = num.y * invZ; o.z = num.z * invZ; o.w = num.w * invZ;
    *(float4*)(out + (size_t)row * DD + db) = o;
}

extern "C" void kernel_launch(void* const* d_in, const int* in_sizes, int n_in,
                              void* d_out, int out_size, void* d_ws, size_t ws_size,
                              hipStream_t stream) {
    const float* x  = (const float*)d_in[0];
    const float* Wq = (const float*)d_in[1];
    const float* Wk = (const float*)d_in[2];
    const float* Wv = (const float*)d_in[3];
    const float* wm = (const float*)d_in[4];
    const float* bm = (const float*)d_in[5];
    float* out = (float*)d_out;
    float* ws = (float*)d_ws;

    size_t off = 0;
    auto alloc = [&](size_t n) {
        float* p = ws + off;
        off += (n + 255) & ~(size_t)255;
        return p;
    };
    float* u        = alloc(2*DD);
    float* a        = alloc(NROWS);
    float* c        = alloc(NROWS);
    float* c_sorted = alloc(NROWS);
    float* e_sorted = alloc(NROWS);
    float* SE       = alloc((size_t)BB*(LL+1));
    int*   perm     = (int*)alloc(NROWS);
    int*   binstart = (int*)alloc((size_t)BB*(NB+2));
    float* hdr      = alloc(2*BB);
    float* V        = alloc((size_t)NROWS*DD);
    float* Pl       = alloc((size_t)NROWS*DD);
    float* Pel      = alloc((size_t)NROWS*DD);
    float* Tp       = alloc((size_t)BB*NC*DD);
    float* Te       = alloc((size_t)BB*NC*DD);
    float* baseP    = alloc((size_t)BB*(NC+1)*DD);
    float* basePe   = alloc((size_t)BB*(NC+1)*DD);

    hipMemsetAsync(u, 0, 2*DD*sizeof(float), stream);
    hipLaunchKernelGGL(k_uvec, dim3(16), dim3(DD), 0, stream, Wq, Wk, wm, u);
    hipLaunchKernelGGL(k_proj, dim3(NROWS/4), dim3(256), 0, stream, x, u, bm, a, c);
    hipLaunchKernelGGL(k_sortish, dim3(BB), dim3(1024), 0, stream,
                       c, binstart, perm, c_sorted, e_sorted, SE, hdr);
    hipLaunchKernelGGL(k_gemm_v, dim3(NROWS/64, DD/128), dim3(128), 0, stream, x, Wv, V);
    hipLaunchKernelGGL(k_scan, dim3(NC, BB), dim3(DD), 0, stream, V, perm, e_sorted, Pl, Pel, Tp, Te);
    hipLaunchKernelGGL(k_base, dim3(BB), dim3(DD), 0, stream, Tp, Te, baseP, basePe);
    hipLaunchKernelGGL(k_out, dim3(NROWS/4), dim3(256), 0, stream,
                       a, hdr, binstart, c_sorted, e_sorted, perm, V,
                       SE, Pl, Pel, baseP, basePe, out);
}

// Round 7
// 148.604 us; speedup vs baseline: 1.1491x; 1.1491x over previous
//
#include <hip/hip_runtime.h>
#include <math.h>

#define BB 4
#define LL 4096
#define DD 256
#define NROWS (BB*LL)      // 16384
#define CHUNK 32
#define NC (LL/CHUNK)      // 128
#define NB 8192            // counting-sort bins

// ---------------- K1: u_q = Wq^T w, u_k = Wk^T w (u pre-zeroed) ----------------
__global__ void k_uvec(const float* __restrict__ Wq, const float* __restrict__ Wk,
                       const float* __restrict__ w, float* __restrict__ u) {
    __shared__ float wl[16];
    int d = threadIdx.x;
    int e0 = blockIdx.x * 16;
    if (d < 16) wl[d] = w[e0 + d];
    __syncthreads();
    float aq = 0.f, ak = 0.f;
    #pragma unroll
    for (int j = 0; j < 16; ++j) {
        float we = wl[j];
        aq = fmaf(Wq[(size_t)(e0 + j)*DD + d], we, aq);
        ak = fmaf(Wk[(size_t)(e0 + j)*DD + d], we, ak);
    }
    atomicAdd(&u[d], aq);
    atomicAdd(&u[DD + d], ak);
}

// ---------------- K4: V = x @ Wv^T, fused a/c projection ----------------
// 64x64 tile, 256 threads (16x16), micro 4x4. Grid (256,4) = 1024 blocks
// -> 4+ blocks/CU (round-2's occupancy) with round-5's conflict-free layout.
// LDS stride-9 [m][kc] float4: slot 9m+kc -> bank group 4(m+kc) mod 32.
//   staging writes (8-lane quantum m fixed, kc 0..7): all 8 groups -> free.
//   A reads (m=ty+16r, kc fixed): 4 addrs 4 groups, 16-way bcast -> free.
//   B reads (n=tx+16s): 16 addrs, 2/group -> free (m136: 2-way is free).
// blockIdx.y==0 blocks also accumulate a=x.uq+b, c=x.uk from the staged
// As slab (2 extra b128 + 16 FMA /thread/K-step; block-uniform guard).
__global__ void __launch_bounds__(256) k_gemm_v(const float* __restrict__ x,
        const float* __restrict__ Wv, const float* __restrict__ u,
        const float* __restrict__ bmlp,
        float* __restrict__ V, float* __restrict__ a, float* __restrict__ c) {
    __shared__ float4 As[64*9];      // 9 KB
    __shared__ float4 Bs[64*9];      // 9 KB
    __shared__ float4 ul[128];       // uq (64 float4) + uk (64 float4)
    __shared__ float prosq[256];
    __shared__ float prosk[256];
    const int tid = threadIdx.x;
    const int rowBase = blockIdx.x * 64;
    const int colBase = blockIdx.y * 64;
    const int ty = tid >> 4;         // [0,16): rows ty + 16r, r<4
    const int tx = tid & 15;         // [0,16): cols tx + 16s, s<4
    const int pr = tid & 63;         // proj row
    const int pq = tid >> 6;         // proj k-quarter (wave id)

    if (tid < 128) ul[tid] = ((const float4*)u)[tid];

    float acc[4][4];
    #pragma unroll
    for (int r = 0; r < 4; ++r)
        #pragma unroll
        for (int s = 0; s < 4; ++s) acc[r][s] = 0.f;
    float aq = 0.f, ak = 0.f;

    for (int k0 = 0; k0 < DD; k0 += 32) {
        __syncthreads();
        // stage A: 64 rows x 8 kc = 512 float4 -> 2/thread
        #pragma unroll
        for (int rep = 0; rep < 2; ++rep) {
            int idx = tid + 256*rep;
            int m = idx >> 3, kc = idx & 7;
            As[m*9 + kc] = *(const float4*)(x + (size_t)(rowBase + m) * DD + k0 + 4*kc);
        }
        // stage B: 64 rows x 8 kc = 512 float4 -> 2/thread
        #pragma unroll
        for (int rep = 0; rep < 2; ++rep) {
            int idx = tid + 256*rep;
            int n = idx >> 3, kc = idx & 7;
            Bs[n*9 + kc] = *(const float4*)(Wv + (size_t)(colBase + n) * DD + k0 + 4*kc);
        }
        __syncthreads();
        if (blockIdx.y == 0) {
            // proj partial: thread covers row pr, kc pair {2pq, 2pq+1}
            #pragma unroll
            for (int h = 0; h < 2; ++h) {
                int kc = pq*2 + h;
                float4 av = As[pr*9 + kc];
                float4 q4 = ul[(k0 >> 2) + kc];
                float4 k4 = ul[64 + (k0 >> 2) + kc];
                aq = fmaf(av.x, q4.x, fmaf(av.y, q4.y, fmaf(av.z, q4.z, fmaf(av.w, q4.w, aq))));
                ak = fmaf(av.x, k4.x, fmaf(av.y, k4.y, fmaf(av.z, k4.z, fmaf(av.w, k4.w, ak))));
            }
        }
        #pragma unroll
        for (int kc = 0; kc < 8; ++kc) {
            float4 af[4], bf[4];
            #pragma unroll
            for (int r = 0; r < 4; ++r) af[r] = As[(ty + 16*r)*9 + kc];
            #pragma unroll
            for (int s = 0; s < 4; ++s) bf[s] = Bs[(tx + 16*s)*9 + kc];
            #pragma unroll
            for (int r = 0; r < 4; ++r)
                #pragma unroll
                for (int s = 0; s < 4; ++s) {
                    acc[r][s] = fmaf(af[r].x, bf[s].x, acc[r][s]);
                    acc[r][s] = fmaf(af[r].y, bf[s].y, acc[r][s]);
                    acc[r][s] = fmaf(af[r].z, bf[s].z, acc[r][s]);
                    acc[r][s] = fmaf(af[r].w, bf[s].w, acc[r][s]);
                }
        }
    }
    #pragma unroll
    for (int r = 0; r < 4; ++r) {
        size_t rowo = (size_t)(rowBase + ty + 16*r) * DD + colBase;
        #pragma unroll
        for (int s = 0; s < 4; ++s)
            V[rowo + tx + 16*s] = acc[r][s];
    }
    if (blockIdx.y == 0) {
        __syncthreads();
        prosq[pq*64 + pr] = aq;
        prosk[pq*64 + pr] = ak;
        __syncthreads();
        if (tid < 64) {
            float sa = prosq[tid] + prosq[64+tid] + prosq[128+tid] + prosq[192+tid];
            float sc = prosk[tid] + prosk[64+tid] + prosk[128+tid] + prosk[192+tid];
            a[rowBase + tid] = sa + bmlp[0];
            c[rowBase + tid] = sc;
        }
    }
}

// ---------------- K3: counting sort by value-bin + SE prefix ----------------
__global__ void __launch_bounds__(1024) k_sortish(const float* __restrict__ c,
        int* __restrict__ binstart_g,       // [BB][NB+2]
        int* __restrict__ perm,             // [BB][LL]
        float* __restrict__ c_sorted, float* __restrict__ e_sorted,
        float* __restrict__ SE,             // [BB][LL+1]
        float* __restrict__ hdr) {          // [BB][2] = {cmin, scale}
    __shared__ float cl[LL];       // 16 KB
    __shared__ int   hist[NB];     // 32 KB
    __shared__ float esl[LL];      // 16 KB
    __shared__ float scrf[64];
    int b = blockIdx.x, tid = threadIdx.x;
    int wave = tid >> 6, lane = tid & 63;
    int* scri = (int*)scrf;

    float4 cv = ((const float4*)(c + (size_t)b*LL))[tid];
    ((float4*)cl)[tid] = cv;
    float cw[4] = {cv.x, cv.y, cv.z, cv.w};
    float mn = fminf(fminf(cw[0],cw[1]), fminf(cw[2],cw[3]));
    float mx = fmaxf(fmaxf(cw[0],cw[1]), fmaxf(cw[2],cw[3]));
    #pragma unroll
    for (int off = 32; off > 0; off >>= 1) {
        mn = fminf(mn, __shfl_down(mn, off));
        mx = fmaxf(mx, __shfl_down(mx, off));
    }
    if (lane == 0) { scrf[wave] = mn; scrf[32 + wave] = mx; }
    __syncthreads();
    if (wave == 0) {
        float m = (lane < 16) ? scrf[lane]      :  3.4e38f;
        float M = (lane < 16) ? scrf[32 + lane] : -3.4e38f;
        #pragma unroll
        for (int off = 32; off > 0; off >>= 1) {
            m = fminf(m, __shfl_down(m, off));
            M = fmaxf(M, __shfl_down(M, off));
        }
        if (lane == 0) { scrf[0] = m; scrf[1] = M; }
    }
    __syncthreads();
    float cmin = scrf[0], cmax = scrf[1];
    float scale = (float)NB / fmaxf(cmax - cmin, 1e-20f);
    __syncthreads();

    ((int4*)hist)[tid] = make_int4(0,0,0,0);
    ((int4*)hist)[tid + 1024] = make_int4(0,0,0,0);
    __syncthreads();

    int bins[4];
    #pragma unroll
    for (int u = 0; u < 4; ++u) {
        int bi = (int)((cw[u] - cmin) * scale);
        bi = bi < 0 ? 0 : (bi > NB-1 ? NB-1 : bi);
        bins[u] = bi;
        atomicAdd(&hist[bi], 1);
    }
    __syncthreads();

    int loc[8]; int base = 0;
    #pragma unroll
    for (int j = 0; j < 8; ++j) { loc[j] = base; base += hist[tid*8 + j]; }
    int incl = base;
    #pragma unroll
    for (int off = 1; off < 64; off <<= 1) {
        int t = __shfl_up(incl, off);
        if (lane >= off) incl += t;
    }
    if (lane == 63) scri[wave] = incl;
    __syncthreads();
    if (wave == 0) {
        int v = (lane < 16) ? scri[lane] : 0;
        int s = v;
        #pragma unroll
        for (int off = 1; off < 16; off <<= 1) {
            int t = __shfl_up(s, off);
            if (lane >= off) s += t;
        }
        if (lane < 16) scri[lane] = s - v;
    }
    __syncthreads();
    int thread_excl = (incl - base) + scri[wave];
    __syncthreads();
    #pragma unroll
    for (int j = 0; j < 8; ++j) {
        int bs = thread_excl + loc[j];
        binstart_g[(size_t)b*(NB+2) + tid*8 + j] = bs;
        hist[tid*8 + j] = bs;
    }
    if (tid == 0) {
        binstart_g[(size_t)b*(NB+2) + NB]     = LL;
        binstart_g[(size_t)b*(NB+2) + NB + 1] = LL;
        hdr[b*2 + 0] = cmin;
        hdr[b*2 + 1] = scale;
    }
    __syncthreads();

    #pragma unroll
    for (int u = 0; u < 4; ++u) {
        int i = tid*4 + u;
        int r = atomicAdd(&hist[bins[u]], 1);
        float e = expf(cmin - cw[u]);
        perm[(size_t)b*LL + r] = i;
        c_sorted[(size_t)b*LL + r] = cw[u];
        e_sorted[(size_t)b*LL + r] = e;
        esl[r] = e;
    }
    __syncthreads();

    float le[4]; float s0 = 0.f;
    #pragma unroll
    for (int u = 0; u < 4; ++u) { le[u] = s0; s0 += esl[tid*4 + u]; }
    float fincl = s0;
    #pragma unroll
    for (int off = 1; off < 64; off <<= 1) {
        float t = __shfl_up(fincl, off);
        if (lane >= off) fincl += t;
    }
    if (lane == 63) scrf[wave] = fincl;
    __syncthreads();
    if (wave == 0) {
        float v = (lane < 16) ? scrf[lane] : 0.f;
        float s = v;
        #pragma unroll
        for (int off = 1; off < 16; off <<= 1) {
            float t = __shfl_up(s, off);
            if (lane >= off) s += t;
        }
        if (lane < 16) scrf[lane] = s - v;
    }
    __syncthreads();
    float texcl = (fincl - s0) + scrf[wave];
    #pragma unroll
    for (int u = 0; u < 4; ++u)
        SE[(size_t)b*(LL+1) + tid*4 + u] = texcl + le[u];
    if (tid == 1023) SE[(size_t)b*(LL+1) + LL] = texcl + s0;
}

// ---------------- K5: chunked exclusive prefix over V in rank order ----------------
__global__ void k_scan(const float* __restrict__ V, const int* __restrict__ perm,
        const float* __restrict__ e_sorted,
        float* __restrict__ Pl, float* __restrict__ Pel,
        float* __restrict__ Tp, float* __restrict__ Te) {
    int b = blockIdx.y, q = blockIdx.x;
    int d = threadIdx.x;
    __shared__ int pj[CHUNK];
    __shared__ float pe[CHUNK];
    if (d < CHUNK) {
        pj[d] = perm[(size_t)b*LL + q*CHUNK + d];
        pe[d] = e_sorted[(size_t)b*LL + q*CHUNK + d];
    }
    __syncthreads();
    float vr[CHUNK];
    #pragma unroll
    for (int r = 0; r < CHUNK; ++r)
        vr[r] = V[((size_t)b*LL + pj[r]) * DD + d];
    float acc = 0.f, acce = 0.f;
    size_t kb = (size_t)b*LL + (size_t)q*CHUNK;
    #pragma unroll
    for (int r = 0; r < CHUNK; ++r) {
        size_t o = (kb + r) * DD + d;
        Pl[o]  = acc;
        Pel[o] = acce;
        acc += vr[r];
        acce = fmaf(pe[r], vr[r], acce);
    }
    size_t to = ((size_t)b*NC + q) * DD + d;
    Tp[to] = acc;
    Te[to] = acce;
}

// ---------------- K6: scan chunk totals -> chunk bases (+ grand total) ----------------
__global__ void k_base(const float* __restrict__ Tp, const float* __restrict__ Te,
        float* __restrict__ baseP, float* __restrict__ basePe) {
    int b = blockIdx.x, d = threadIdx.x;
    float acc = 0.f, acce = 0.f;
    #pragma unroll 16
    for (int q = 0; q < NC; ++q) {
        size_t o = ((size_t)b*(NC+1) + q) * DD + d;
        baseP[o] = acc; basePe[o] = acce;
        size_t ti = ((size_t)b*NC + q) * DD + d;
        acc += Tp[ti]; acce += Te[ti];
    }
    size_t o = ((size_t)b*(NC+1) + NC) * DD + d;
    baseP[o] = acc; basePe[o] = acce;
}

// ---------------- K7: per-row output, O(1) bin lookup + exact boundary fix ----------------
__global__ void k_out(const float* __restrict__ a, const float* __restrict__ hdr,
                      const int* __restrict__ binstart,
                      const float* __restrict__ c_sorted, const float* __restrict__ e_sorted,
                      const int* __restrict__ perm, const float* __restrict__ V,
                      const float* __restrict__ SE,
                      const float* __restrict__ Pl, const float* __restrict__ Pel,
                      const float* __restrict__ baseP, const float* __restrict__ basePe,
                      float* __restrict__ out) {
    int row = blockIdx.x * 4 + (threadIdx.x >> 6);
    int lane = threadIdx.x & 63;
    int b = row >> 12;
    float ai = a[row];
    float cmin = hdr[b*2 + 0], scale = hdr[b*2 + 1];
    float t = (ai - cmin) * scale;
    int ib = t < 0.f ? 0 : (t >= (float)NB ? NB : (int)t);
    int k    = binstart[(size_t)b*(NB+2) + ib];
    int kend = binstart[(size_t)b*(NB+2) + ib + 1];
    float alpha = expf(cmin - ai);
    float Z = fmaf(alpha, (float)(LL - k), SE[(size_t)b*(LL+1) + k]);
    size_t db = (size_t)lane * 4;
    size_t totoff = ((size_t)b * (NC+1) + NC) * DD + db;
    float4 ptot  = *(const float4*)(baseP  + totoff);
    float4 pk, pek;
    if (k < LL) {
        int q = k >> 5;
        size_t po = ((size_t)b * LL + k) * DD + db;
        size_t bo = ((size_t)b * (NC+1) + q) * DD + db;
        float4 pl = *(const float4*)(Pl    + po);
        float4 bp = *(const float4*)(baseP + bo);
        float4 pe = *(const float4*)(Pel    + po);
        float4 be = *(const float4*)(basePe + bo);
        pk.x = pl.x + bp.x; pk.y = pl.y + bp.y; pk.z = pl.z + bp.z; pk.w = pl.w + bp.w;
        pek.x = pe.x + be.x; pek.y = pe.y + be.y; pek.z = pe.z + be.z; pek.w = pe.w + be.w;
    } else {
        pk = ptot;
        float4 pt = *(const float4*)(basePe + totoff);
        pek = pt;
    }
    float4 num;
    num.x = fmaf(alpha, ptot.x - pk.x, pek.x);
    num.y = fmaf(alpha, ptot.y - pk.y, pek.y);
    num.z = fmaf(alpha, ptot.z - pk.z, pek.z);
    num.w = fmaf(alpha, ptot.w - pk.w, pek.w);
    for (int r = k; r < kend; ++r) {
        float cr = c_sorted[(size_t)b*LL + r];
        if (cr < ai) {
            float w = e_sorted[(size_t)b*LL + r] - alpha;
            int j = perm[(size_t)b*LL + r];
            float4 v = *(const float4*)(V + ((size_t)b*LL + j) * DD + db);
            num.x = fmaf(w, v.x, num.x);
            num.y = fmaf(w, v.y, num.y);
            num.z = fmaf(w, v.z, num.z);
            num.w = fmaf(w, v.w, num.w);
            Z += w;
        }
    }
    float invZ = 1.f / Z;
    float4 o;
    o.x = num.x * invZ; o.y = num.y * invZ; o.z = num.z * invZ; o.w = num.w * invZ;
    *(float4*)(out + (size_t)row * DD + db) = o;
}

extern "C" void kernel_launch(void* const* d_in, const int* in_sizes, int n_in,
                              void* d_out, int out_size, void* d_ws, size_t ws_size,
                              hipStream_t stream) {
    const float* x  = (const float*)d_in[0];
    const float* Wq = (const float*)d_in[1];
    const float* Wk = (const float*)d_in[2];
    const float* Wv = (const float*)d_in[3];
    const float* wm = (const float*)d_in[4];
    const float* bm = (const float*)d_in[5];
    float* out = (float*)d_out;
    float* ws = (float*)d_ws;

    size_t off = 0;
    auto alloc = [&](size_t n) {
        float* p = ws + off;
        off += (n + 255) & ~(size_t)255;
        return p;
    };
    float* u        = alloc(2*DD);
    float* a        = alloc(NROWS);
    float* c        = alloc(NROWS);
    float* c_sorted = alloc(NROWS);
    float* e_sorted = alloc(NROWS);
    float* SE       = alloc((size_t)BB*(LL+1));
    int*   perm     = (int*)alloc(NROWS);
    int*   binstart = (int*)alloc((size_t)BB*(NB+2));
    float* hdr      = alloc(2*BB);
    float* V        = alloc((size_t)NROWS*DD);
    float* Pl       = alloc((size_t)NROWS*DD);
    float* Pel      = alloc((size_t)NROWS*DD);
    float* Tp       = alloc((size_t)BB*NC*DD);
    float* Te       = alloc((size_t)BB*NC*DD);
    float* baseP    = alloc((size_t)BB*(NC+1)*DD);
    float* basePe   = alloc((size_t)BB*(NC+1)*DD);

    hipMemsetAsync(u, 0, 2*DD*sizeof(float), stream);
    hipLaunchKernelGGL(k_uvec, dim3(16), dim3(DD), 0, stream, Wq, Wk, wm, u);
    hipLaunchKernelGGL(k_gemm_v, dim3(NROWS/64, DD/64), dim3(256), 0, stream,
                       x, Wv, u, bm, V, a, c);
    hipLaunchKernelGGL(k_sortish, dim3(BB), dim3(1024), 0, stream,
                       c, binstart, perm, c_sorted, e_sorted, SE, hdr);
    hipLaunchKernelGGL(k_scan, dim3(NC, BB), dim3(DD), 0, stream, V, perm, e_sorted, Pl, Pel, Tp, Te);
    hipLaunchKernelGGL(k_base, dim3(BB), dim3(DD), 0, stream, Tp, Te, baseP, basePe);
    hipLaunchKernelGGL(k_out, dim3(NROWS/4), dim3(256), 0, stream,
                       a, hdr, binstart, c_sorted, e_sorted, perm, V,
                       SE, Pl, Pel, baseP, basePe, out);
}

// Round 8
// 146.216 us; speedup vs baseline: 1.1678x; 1.0163x over previous
//
#include <hip/hip_runtime.h>
#include <math.h>

#define BB 4
#define LL 4096
#define DD 256
#define NROWS (BB*LL)      // 16384
#define CHUNK 32
#define NC (LL/CHUNK)      // 128
#define NB 8192            // counting-sort bins

typedef __bf16 bf16x8 __attribute__((ext_vector_type(8)));
typedef __bf16 bf16x4 __attribute__((ext_vector_type(4)));
typedef float floatx4 __attribute__((ext_vector_type(4)));

// ---------------- K1: u_q = Wq^T w, u_k = Wk^T w (u pre-zeroed) ----------------
__global__ void k_uvec(const float* __restrict__ Wq, const float* __restrict__ Wk,
                       const float* __restrict__ w, float* __restrict__ u) {
    __shared__ float wl[16];
    int d = threadIdx.x;
    int e0 = blockIdx.x * 16;
    if (d < 16) wl[d] = w[e0 + d];
    __syncthreads();
    float aq = 0.f, ak = 0.f;
    #pragma unroll
    for (int j = 0; j < 16; ++j) {
        float we = wl[j];
        aq = fmaf(Wq[(size_t)(e0 + j)*DD + d], we, aq);
        ak = fmaf(Wk[(size_t)(e0 + j)*DD + d], we, ak);
    }
    atomicAdd(&u[d], aq);
    atomicAdd(&u[DD + d], ak);
}

// ---------------- K2: split x -> xh+xl (bf16), fused a/c projection; also Wv ----------------
// blocks [0,4096): 4 x-rows each (lane=64 per row); blocks [4096,4160): 4 Wv-rows each.
__global__ void k_split(const float* __restrict__ x, const float* __restrict__ Wv,
                        const float* __restrict__ u, const float* __restrict__ bmlp,
                        __bf16* __restrict__ xh, __bf16* __restrict__ xl,
                        __bf16* __restrict__ Wh, __bf16* __restrict__ Wl,
                        float* __restrict__ a, float* __restrict__ c) {
    int lane = threadIdx.x & 63;
    if (blockIdx.x < NROWS/4) {
        int row = blockIdx.x * 4 + (threadIdx.x >> 6);
        float4 xv = ((const float4*)(x + (size_t)row * DD))[lane];
        __bf16 h0 = (__bf16)xv.x, h1 = (__bf16)xv.y, h2 = (__bf16)xv.z, h3 = (__bf16)xv.w;
        __bf16 l0 = (__bf16)(xv.x - (float)h0), l1 = (__bf16)(xv.y - (float)h1);
        __bf16 l2 = (__bf16)(xv.z - (float)h2), l3 = (__bf16)(xv.w - (float)h3);
        bf16x4 hv = {h0, h1, h2, h3};
        bf16x4 lv = {l0, l1, l2, l3};
        *(bf16x4*)(xh + (size_t)row * DD + lane*4) = hv;
        *(bf16x4*)(xl + (size_t)row * DD + lane*4) = lv;
        float4 uq = ((const float4*)u)[lane];
        float4 uk = ((const float4*)(u + DD))[lane];
        float sq = xv.x*uq.x + xv.y*uq.y + xv.z*uq.z + xv.w*uq.w;
        float sk = xv.x*uk.x + xv.y*uk.y + xv.z*uk.z + xv.w*uk.w;
        #pragma unroll
        for (int off = 32; off > 0; off >>= 1) {
            sq += __shfl_down(sq, off);
            sk += __shfl_down(sk, off);
        }
        if (lane == 0) {
            a[row] = sq + bmlp[0];
            c[row] = sk;
        }
    } else {
        int wrow = (blockIdx.x - NROWS/4) * 4 + (threadIdx.x >> 6);
        float4 wv = ((const float4*)(Wv + (size_t)wrow * DD))[lane];
        __bf16 h0 = (__bf16)wv.x, h1 = (__bf16)wv.y, h2 = (__bf16)wv.z, h3 = (__bf16)wv.w;
        __bf16 l0 = (__bf16)(wv.x - (float)h0), l1 = (__bf16)(wv.y - (float)h1);
        __bf16 l2 = (__bf16)(wv.z - (float)h2), l3 = (__bf16)(wv.w - (float)h3);
        bf16x4 hv = {h0, h1, h2, h3};
        bf16x4 lv = {l0, l1, l2, l3};
        *(bf16x4*)(Wh + (size_t)wrow * DD + lane*4) = hv;
        *(bf16x4*)(Wl + (size_t)wrow * DD + lane*4) = lv;
    }
}

// ---------------- K4: V = x @ Wv^T via split-bf16 MFMA ----------------
// V = (xh+xl)(Wh+Wl)^T ~= xh.Wh^T + xh.Wl^T + xl.Wh^T  (xl.Wl ~ 2^-18, dropped).
// Block: 32 rows x 256 cols (full N), 256 thr = 4 waves; wave w owns cols
// [64w, 64w+64): 4 col-tiles x 2 row-tiles of 16x16, K-steps of 32.
// mfma_f32_16x16x32_bf16 layouts (verified m89/m92): A[m=lane&15][k=quad*8+j],
// B[n=lane&15][k=quad*8+j] (Wv rows = B^T form), C/D row=quad*4+reg, col=lane&15.
// LDS rows padded to 40 elems (80 B): 16B-aligned b128, bank group 20m%32 ->
// 8 distinct groups, 2 addrs/group = free (m136). 45 KB -> 3 blocks/CU.
__global__ void __launch_bounds__(256) k_gemm_mfma(
        const __bf16* __restrict__ xh, const __bf16* __restrict__ xl,
        const __bf16* __restrict__ Wh, const __bf16* __restrict__ Wl,
        float* __restrict__ V) {
    __shared__ __bf16 Ah[32*40];    // 2.5 KB
    __shared__ __bf16 Al[32*40];
    __shared__ __bf16 Bh[256*40];   // 20 KB
    __shared__ __bf16 Bl[256*40];
    const int tid = threadIdx.x;
    const int wave = tid >> 6, lane = tid & 63;
    const int rowBase = blockIdx.x * 32;
    const int quad = lane >> 4, l16 = lane & 15;

    floatx4 acc[2][4];
    #pragma unroll
    for (int rt = 0; rt < 2; ++rt)
        #pragma unroll
        for (int ct = 0; ct < 4; ++ct)
            acc[rt][ct] = (floatx4){0.f, 0.f, 0.f, 0.f};

    for (int k0 = 0; k0 < DD; k0 += 32) {
        __syncthreads();
        // stage x slab: 32 rows x 32 k, thread t -> row t>>3, k-quarter (t&7)*4
        {
            int row = tid >> 3, kq = (tid & 7) * 4;
            *(bf16x4*)&Ah[row*40 + kq] = *(const bf16x4*)(xh + (size_t)(rowBase + row)*DD + k0 + kq);
            *(bf16x4*)&Al[row*40 + kq] = *(const bf16x4*)(xl + (size_t)(rowBase + row)*DD + k0 + kq);
        }
        // stage W slab: 256 rows x 32 k, thread t -> row t, 4x8 bf16 per array
        {
            int n = tid;
            #pragma unroll
            for (int p = 0; p < 4; ++p) {
                *(bf16x8*)&Bh[n*40 + p*8] = *(const bf16x8*)(Wh + (size_t)n*DD + k0 + p*8);
                *(bf16x8*)&Bl[n*40 + p*8] = *(const bf16x8*)(Wl + (size_t)n*DD + k0 + p*8);
            }
        }
        __syncthreads();
        bf16x8 ah[2], al[2], bh[4], bl[4];
        #pragma unroll
        for (int rt = 0; rt < 2; ++rt) {
            int m = rt*16 + l16;
            ah[rt] = *(bf16x8*)&Ah[m*40 + quad*8];
            al[rt] = *(bf16x8*)&Al[m*40 + quad*8];
        }
        #pragma unroll
        for (int ct = 0; ct < 4; ++ct) {
            int n = wave*64 + ct*16 + l16;
            bh[ct] = *(bf16x8*)&Bh[n*40 + quad*8];
            bl[ct] = *(bf16x8*)&Bl[n*40 + quad*8];
        }
        #pragma unroll
        for (int rt = 0; rt < 2; ++rt)
            #pragma unroll
            for (int ct = 0; ct < 4; ++ct) {
                acc[rt][ct] = __builtin_amdgcn_mfma_f32_16x16x32_bf16(ah[rt], bh[ct], acc[rt][ct], 0, 0, 0);
                acc[rt][ct] = __builtin_amdgcn_mfma_f32_16x16x32_bf16(ah[rt], bl[ct], acc[rt][ct], 0, 0, 0);
                acc[rt][ct] = __builtin_amdgcn_mfma_f32_16x16x32_bf16(al[rt], bh[ct], acc[rt][ct], 0, 0, 0);
            }
    }
    #pragma unroll
    for (int rt = 0; rt < 2; ++rt)
        #pragma unroll
        for (int ct = 0; ct < 4; ++ct)
            #pragma unroll
            for (int i = 0; i < 4; ++i) {
                int row = rowBase + rt*16 + quad*4 + i;
                int col = wave*64 + ct*16 + l16;
                V[(size_t)row*DD + col] = acc[rt][ct][i];
            }
}

// ---------------- K3: counting sort by value-bin + SE prefix ----------------
__global__ void __launch_bounds__(1024) k_sortish(const float* __restrict__ c,
        int* __restrict__ binstart_g, int* __restrict__ perm,
        float* __restrict__ c_sorted, float* __restrict__ e_sorted,
        float* __restrict__ SE, float* __restrict__ hdr) {
    __shared__ float cl[LL];
    __shared__ int   hist[NB];
    __shared__ float esl[LL];
    __shared__ float scrf[64];
    int b = blockIdx.x, tid = threadIdx.x;
    int wave = tid >> 6, lane = tid & 63;
    int* scri = (int*)scrf;

    float4 cv = ((const float4*)(c + (size_t)b*LL))[tid];
    ((float4*)cl)[tid] = cv;
    float cw[4] = {cv.x, cv.y, cv.z, cv.w};
    float mn = fminf(fminf(cw[0],cw[1]), fminf(cw[2],cw[3]));
    float mx = fmaxf(fmaxf(cw[0],cw[1]), fmaxf(cw[2],cw[3]));
    #pragma unroll
    for (int off = 32; off > 0; off >>= 1) {
        mn = fminf(mn, __shfl_down(mn, off));
        mx = fmaxf(mx, __shfl_down(mx, off));
    }
    if (lane == 0) { scrf[wave] = mn; scrf[32 + wave] = mx; }
    __syncthreads();
    if (wave == 0) {
        float m = (lane < 16) ? scrf[lane]      :  3.4e38f;
        float M = (lane < 16) ? scrf[32 + lane] : -3.4e38f;
        #pragma unroll
        for (int off = 32; off > 0; off >>= 1) {
            m = fminf(m, __shfl_down(m, off));
            M = fmaxf(M, __shfl_down(M, off));
        }
        if (lane == 0) { scrf[0] = m; scrf[1] = M; }
    }
    __syncthreads();
    float cmin = scrf[0], cmax = scrf[1];
    float scale = (float)NB / fmaxf(cmax - cmin, 1e-20f);
    __syncthreads();

    ((int4*)hist)[tid] = make_int4(0,0,0,0);
    ((int4*)hist)[tid + 1024] = make_int4(0,0,0,0);
    __syncthreads();

    int bins[4];
    #pragma unroll
    for (int u = 0; u < 4; ++u) {
        int bi = (int)((cw[u] - cmin) * scale);
        bi = bi < 0 ? 0 : (bi > NB-1 ? NB-1 : bi);
        bins[u] = bi;
        atomicAdd(&hist[bi], 1);
    }
    __syncthreads();

    int loc[8]; int base = 0;
    #pragma unroll
    for (int j = 0; j < 8; ++j) { loc[j] = base; base += hist[tid*8 + j]; }
    int incl = base;
    #pragma unroll
    for (int off = 1; off < 64; off <<= 1) {
        int t = __shfl_up(incl, off);
        if (lane >= off) incl += t;
    }
    if (lane == 63) scri[wave] = incl;
    __syncthreads();
    if (wave == 0) {
        int v = (lane < 16) ? scri[lane] : 0;
        int s = v;
        #pragma unroll
        for (int off = 1; off < 16; off <<= 1) {
            int t = __shfl_up(s, off);
            if (lane >= off) s += t;
        }
        if (lane < 16) scri[lane] = s - v;
    }
    __syncthreads();
    int thread_excl = (incl - base) + scri[wave];
    __syncthreads();
    #pragma unroll
    for (int j = 0; j < 8; ++j) {
        int bs = thread_excl + loc[j];
        binstart_g[(size_t)b*(NB+2) + tid*8 + j] = bs;
        hist[tid*8 + j] = bs;
    }
    if (tid == 0) {
        binstart_g[(size_t)b*(NB+2) + NB]     = LL;
        binstart_g[(size_t)b*(NB+2) + NB + 1] = LL;
        hdr[b*2 + 0] = cmin;
        hdr[b*2 + 1] = scale;
    }
    __syncthreads();

    #pragma unroll
    for (int u = 0; u < 4; ++u) {
        int i = tid*4 + u;
        int r = atomicAdd(&hist[bins[u]], 1);
        float e = expf(cmin - cw[u]);
        perm[(size_t)b*LL + r] = i;
        c_sorted[(size_t)b*LL + r] = cw[u];
        e_sorted[(size_t)b*LL + r] = e;
        esl[r] = e;
    }
    __syncthreads();

    float le[4]; float s0 = 0.f;
    #pragma unroll
    for (int u = 0; u < 4; ++u) { le[u] = s0; s0 += esl[tid*4 + u]; }
    float fincl = s0;
    #pragma unroll
    for (int off = 1; off < 64; off <<= 1) {
        float t = __shfl_up(fincl, off);
        if (lane >= off) fincl += t;
    }
    if (lane == 63) scrf[wave] = fincl;
    __syncthreads();
    if (wave == 0) {
        float v = (lane < 16) ? scrf[lane] : 0.f;
        float s = v;
        #pragma unroll
        for (int off = 1; off < 16; off <<= 1) {
            float t = __shfl_up(s, off);
            if (lane >= off) s += t;
        }
        if (lane < 16) scrf[lane] = s - v;
    }
    __syncthreads();
    float texcl = (fincl - s0) + scrf[wave];
    #pragma unroll
    for (int u = 0; u < 4; ++u)
        SE[(size_t)b*(LL+1) + tid*4 + u] = texcl + le[u];
    if (tid == 1023) SE[(size_t)b*(LL+1) + LL] = texcl + s0;
}

// ---------------- K5: chunked exclusive prefix over V in rank order ----------------
__global__ void k_scan(const float* __restrict__ V, const int* __restrict__ perm,
        const float* __restrict__ e_sorted,
        float* __restrict__ Pl, float* __restrict__ Pel,
        float* __restrict__ Tp, float* __restrict__ Te) {
    int b = blockIdx.y, q = blockIdx.x;
    int d = threadIdx.x;
    __shared__ int pj[CHUNK];
    __shared__ float pe[CHUNK];
    if (d < CHUNK) {
        pj[d] = perm[(size_t)b*LL + q*CHUNK + d];
        pe[d] = e_sorted[(size_t)b*LL + q*CHUNK + d];
    }
    __syncthreads();
    float vr[CHUNK];
    #pragma unroll
    for (int r = 0; r < CHUNK; ++r)
        vr[r] = V[((size_t)b*LL + pj[r]) * DD + d];
    float acc = 0.f, acce = 0.f;
    size_t kb = (size_t)b*LL + (size_t)q*CHUNK;
    #pragma unroll
    for (int r = 0; r < CHUNK; ++r) {
        size_t o = (kb + r) * DD + d;
        Pl[o]  = acc;
        Pel[o] = acce;
        acc += vr[r];
        acce = fmaf(pe[r], vr[r], acce);
    }
    size_t to = ((size_t)b*NC + q) * DD + d;
    Tp[to] = acc;
    Te[to] = acce;
}

// ---------------- K6: scan chunk totals -> chunk bases (+ grand total) ----------------
__global__ void k_base(const float* __restrict__ Tp, const float* __restrict__ Te,
        float* __restrict__ baseP, float* __restrict__ basePe) {
    int b = blockIdx.x, d = threadIdx.x;
    float acc = 0.f, acce = 0.f;
    #pragma unroll 16
    for (int q = 0; q < NC; ++q) {
        size_t o = ((size_t)b*(NC+1) + q) * DD + d;
        baseP[o] = acc; basePe[o] = acce;
        size_t ti = ((size_t)b*NC + q) * DD + d;
        acc += Tp[ti]; acce += Te[ti];
    }
    size_t o = ((size_t)b*(NC+1) + NC) * DD + d;
    baseP[o] = acc; basePe[o] = acce;
}

// ---------------- K7: per-row output, O(1) bin lookup + exact boundary fix ----------------
__global__ void k_out(const float* __restrict__ a, const float* __restrict__ hdr,
                      const int* __restrict__ binstart,
                      const float* __restrict__ c_sorted, const float* __restrict__ e_sorted,
                      const int* __restrict__ perm, const float* __restrict__ V,
                      const float* __restrict__ SE,
                      const float* __restrict__ Pl, const float* __restrict__ Pel,
                      const float* __restrict__ baseP, const float* __restrict__ basePe,
                      float* __restrict__ out) {
    int row = blockIdx.x * 4 + (threadIdx.x >> 6);
    int lane = threadIdx.x & 63;
    int b = row >> 12;
    float ai = a[row];
    float cmin = hdr[b*2 + 0], scale = hdr[b*2 + 1];
    float t = (ai - cmin) * scale;
    int ib = t < 0.f ? 0 : (t >= (float)NB ? NB : (int)t);
    int k    = binstart[(size_t)b*(NB+2) + ib];
    int kend = binstart[(size_t)b*(NB+2) + ib + 1];
    float alpha = expf(cmin - ai);
    float Z = fmaf(alpha, (float)(LL - k), SE[(size_t)b*(LL+1) + k]);
    size_t db = (size_t)lane * 4;
    size_t totoff = ((size_t)b * (NC+1) + NC) * DD + db;
    float4 ptot  = *(const float4*)(baseP  + totoff);
    float4 pk, pek;
    if (k < LL) {
        int q = k >> 5;
        size_t po = ((size_t)b * LL + k) * DD + db;
        size_t bo = ((size_t)b * (NC+1) + q) * DD + db;
        float4 pl = *(const float4*)(Pl    + po);
        float4 bp = *(const float4*)(baseP + bo);
        float4 pe = *(const float4*)(Pel    + po);
        float4 be = *(const float4*)(basePe + bo);
        pk.x = pl.x + bp.x; pk.y = pl.y + bp.y; pk.z = pl.z + bp.z; pk.w = pl.w + bp.w;
        pek.x = pe.x + be.x; pek.y = pe.y + be.y; pek.z = pe.z + be.z; pek.w = pe.w + be.w;
    } else {
        pk = ptot;
        float4 pt = *(const float4*)(basePe + totoff);
        pek = pt;
    }
    float4 num;
    num.x = fmaf(alpha, ptot.x - pk.x, pek.x);
    num.y = fmaf(alpha, ptot.y - pk.y, pek.y);
    num.z = fmaf(alpha, ptot.z - pk.z, pek.z);
    num.w = fmaf(alpha, ptot.w - pk.w, pek.w);
    for (int r = k; r < kend; ++r) {
        float cr = c_sorted[(size_t)b*LL + r];
        if (cr < ai) {
            float w = e_sorted[(size_t)b*LL + r] - alpha;
            int j = perm[(size_t)b*LL + r];
            float4 v = *(const float4*)(V + ((size_t)b*LL + j) * DD + db);
            num.x = fmaf(w, v.x, num.x);
            num.y = fmaf(w, v.y, num.y);
            num.z = fmaf(w, v.z, num.z);
            num.w = fmaf(w, v.w, num.w);
            Z += w;
        }
    }
    float invZ = 1.f / Z;
    float4 o;
    o.x = num.x * invZ; o.y = num.y * invZ; o.z = num.z * invZ; o.w = num.w * invZ;
    *(float4*)(out + (size_t)row * DD + db) = o;
}

extern "C" void kernel_launch(void* const* d_in, const int* in_sizes, int n_in,
                              void* d_out, int out_size, void* d_ws, size_t ws_size,
                              hipStream_t stream) {
    const float* x  = (const float*)d_in[0];
    const float* Wq = (const float*)d_in[1];
    const float* Wk = (const float*)d_in[2];
    const float* Wv = (const float*)d_in[3];
    const float* wm = (const float*)d_in[4];
    const float* bm = (const float*)d_in[5];
    float* out = (float*)d_out;
    float* ws = (float*)d_ws;

    size_t off = 0;
    auto alloc = [&](size_t n) {      // n in floats
        float* p = ws + off;
        off += (n + 255) & ~(size_t)255;
        return p;
    };
    float* u        = alloc(2*DD);
    float* a        = alloc(NROWS);
    float* c        = alloc(NROWS);
    float* c_sorted = alloc(NROWS);
    float* e_sorted = alloc(NROWS);
    float* SE       = alloc((size_t)BB*(LL+1));
    int*   perm     = (int*)alloc(NROWS);
    int*   binstart = (int*)alloc((size_t)BB*(NB+2));
    float* hdr      = alloc(2*BB);
    float* V        = alloc((size_t)NROWS*DD);
    float* Pl       = alloc((size_t)NROWS*DD);
    float* Pel      = alloc((size_t)NROWS*DD);
    float* Tp       = alloc((size_t)BB*NC*DD);
    float* Te       = alloc((size_t)BB*NC*DD);
    float* baseP    = alloc((size_t)BB*(NC+1)*DD);
    float* basePe   = alloc((size_t)BB*(NC+1)*DD);
    __bf16* xh      = (__bf16*)alloc((size_t)NROWS*DD/2);
    __bf16* xl      = (__bf16*)alloc((size_t)NROWS*DD/2);
    __bf16* Wh      = (__bf16*)alloc((size_t)DD*DD/2);
    __bf16* Wl      = (__bf16*)alloc((size_t)DD*DD/2);

    hipMemsetAsync(u, 0, 2*DD*sizeof(float), stream);
    hipLaunchKernelGGL(k_uvec, dim3(16), dim3(DD), 0, stream, Wq, Wk, wm, u);
    hipLaunchKernelGGL(k_split, dim3(NROWS/4 + DD/4), dim3(256), 0, stream,
                       x, Wv, u, bm, xh, xl, Wh, Wl, a, c);
    hipLaunchKernelGGL(k_gemm_mfma, dim3(NROWS/32), dim3(256), 0, stream,
                       xh, xl, Wh, Wl, V);
    hipLaunchKernelGGL(k_sortish, dim3(BB), dim3(1024), 0, stream,
                       c, binstart, perm, c_sorted, e_sorted, SE, hdr);
    hipLaunchKernelGGL(k_scan, dim3(NC, BB), dim3(DD), 0, stream, V, perm, e_sorted, Pl, Pel, Tp, Te);
    hipLaunchKernelGGL(k_base, dim3(BB), dim3(DD), 0, stream, Tp, Te, baseP, basePe);
    hipLaunchKernelGGL(k_out, dim3(NROWS/4), dim3(256), 0, stream,
                       a, hdr, binstart, c_sorted, e_sorted, perm, V,
                       SE, Pl, Pel, baseP, basePe, out);
}

// Round 9
// 137.472 us; speedup vs baseline: 1.2421x; 1.0636x over previous
//
#include <hip/hip_runtime.h>
#include <math.h>

#define BB 4
#define LL 4096
#define DD 256
#define NROWS (BB*LL)      // 16384
#define CHUNK 32
#define NC (LL/CHUNK)      // 128
#define NB 8192            // counting-sort bins

typedef __bf16 bf16x8 __attribute__((ext_vector_type(8)));
typedef __bf16 bf16x4 __attribute__((ext_vector_type(4)));
typedef float floatx4 __attribute__((ext_vector_type(4)));

// ---------------- K1: u = {Wq^T w, Wk^T w} (u pre-zeroed) + split Wv -> Wh+Wl ----------------
// 16 blocks; block g handles e-rows [16g, 16g+16) for all three matrices.
__global__ void k_prep(const float* __restrict__ Wq, const float* __restrict__ Wk,
                       const float* __restrict__ Wv, const float* __restrict__ w,
                       float* __restrict__ u,
                       __bf16* __restrict__ Wh, __bf16* __restrict__ Wl) {
    __shared__ float wl[16];
    int d = threadIdx.x;
    int e0 = blockIdx.x * 16;
    if (d < 16) wl[d] = w[e0 + d];
    __syncthreads();
    float aq = 0.f, ak = 0.f;
    #pragma unroll
    for (int j = 0; j < 16; ++j) {
        float we = wl[j];
        aq = fmaf(Wq[(size_t)(e0 + j)*DD + d], we, aq);
        ak = fmaf(Wk[(size_t)(e0 + j)*DD + d], we, ak);
        float wv = Wv[(size_t)(e0 + j)*DD + d];
        __bf16 h = (__bf16)wv;
        Wh[(size_t)(e0 + j)*DD + d] = h;
        Wl[(size_t)(e0 + j)*DD + d] = (__bf16)(wv - (float)h);
    }
    atomicAdd(&u[d], aq);
    atomicAdd(&u[DD + d], ak);
}

// ---------------- K2: V = x @ Wv^T via split-bf16 MFMA, fused split + a/c proj ----------------
// V = (xh+xl)(Wh+Wl)^T ~= xh.Wh^T + xh.Wl^T + xl.Wh^T  (xl.Wl ~ 2^-18, dropped;
// verified r8: absmax unchanged).
// Block: 32 rows x 256 cols (full N), 256 thr = 4 waves; wave w owns cols [64w,64w+64).
// A: x read fp32 ONCE, split in-register during staging -> Ah/Al LDS (pad 40 elems:
//   80 B rows, 16B-aligned b128 reads, ~2 addrs/bank = free per m136).
// B: NO LDS -- Wh/Wl (256 KB) direct from L2 as bf16x8 fragments, m89 layout
//   B[n=lane&15][k=quad*8+j]. Removes round-8's 40 KB/step LDS-write bottleneck.
// Proj: a = x.uq + b, c = x.uk accumulated on the staged fp32 x values.
__global__ void __launch_bounds__(256) k_gemm_mfma(
        const float* __restrict__ x,
        const __bf16* __restrict__ Wh, const __bf16* __restrict__ Wl,
        const float* __restrict__ u, const float* __restrict__ bmlp,
        float* __restrict__ V, float* __restrict__ a, float* __restrict__ c) {
    __shared__ __bf16 Ah[32*40];    // 2.5 KB
    __shared__ __bf16 Al[32*40];
    __shared__ float4 ul[128];      // uq (64 float4) + uk (64 float4)
    __shared__ float pros[512];
    const int tid = threadIdx.x;
    const int wave = tid >> 6, lane = tid & 63;
    const int rowBase = blockIdx.x * 32;
    const int quad = lane >> 4, l16 = lane & 15;
    const int srow = tid >> 3, skq = (tid & 7) * 4;   // staging: 8 thr/row

    if (tid < 128) ul[tid] = ((const float4*)u)[tid];

    floatx4 acc[2][4];
    #pragma unroll
    for (int rt = 0; rt < 2; ++rt)
        #pragma unroll
        for (int ct = 0; ct < 4; ++ct)
            acc[rt][ct] = (floatx4){0.f, 0.f, 0.f, 0.f};
    float aq = 0.f, ak = 0.f;

    for (int k0 = 0; k0 < DD; k0 += 32) {
        __syncthreads();
        // stage + split x slab (32 rows x 32 k), 1 float4/thread
        float4 xv = *(const float4*)(x + (size_t)(rowBase + srow)*DD + k0 + skq);
        __bf16 h0 = (__bf16)xv.x, h1 = (__bf16)xv.y, h2 = (__bf16)xv.z, h3 = (__bf16)xv.w;
        bf16x4 hv = {h0, h1, h2, h3};
        bf16x4 lv = {(__bf16)(xv.x - (float)h0), (__bf16)(xv.y - (float)h1),
                     (__bf16)(xv.z - (float)h2), (__bf16)(xv.w - (float)h3)};
        *(bf16x4*)&Ah[srow*40 + skq] = hv;
        *(bf16x4*)&Al[srow*40 + skq] = lv;
        // fused projection partials on the same x values
        float4 q4 = ul[(k0 >> 2) + (tid & 7)];
        float4 k4 = ul[64 + (k0 >> 2) + (tid & 7)];
        aq = fmaf(xv.x, q4.x, fmaf(xv.y, q4.y, fmaf(xv.z, q4.z, fmaf(xv.w, q4.w, aq))));
        ak = fmaf(xv.x, k4.x, fmaf(xv.y, k4.y, fmaf(xv.z, k4.z, fmaf(xv.w, k4.w, ak))));
        __syncthreads();
        bf16x8 ah[2], al[2];
        #pragma unroll
        for (int rt = 0; rt < 2; ++rt) {
            int m = rt*16 + l16;
            ah[rt] = *(bf16x8*)&Ah[m*40 + quad*8];
            al[rt] = *(bf16x8*)&Al[m*40 + quad*8];
        }
        #pragma unroll
        for (int ct = 0; ct < 4; ++ct) {
            int n = wave*64 + ct*16 + l16;
            bf16x8 bh = *(const bf16x8*)(Wh + (size_t)n*DD + k0 + quad*8);
            bf16x8 bl = *(const bf16x8*)(Wl + (size_t)n*DD + k0 + quad*8);
            #pragma unroll
            for (int rt = 0; rt < 2; ++rt) {
                acc[rt][ct] = __builtin_amdgcn_mfma_f32_16x16x32_bf16(ah[rt], bh, acc[rt][ct], 0, 0, 0);
                acc[rt][ct] = __builtin_amdgcn_mfma_f32_16x16x32_bf16(ah[rt], bl, acc[rt][ct], 0, 0, 0);
                acc[rt][ct] = __builtin_amdgcn_mfma_f32_16x16x32_bf16(al[rt], bh, acc[rt][ct], 0, 0, 0);
            }
        }
    }
    #pragma unroll
    for (int rt = 0; rt < 2; ++rt)
        #pragma unroll
        for (int ct = 0; ct < 4; ++ct)
            #pragma unroll
            for (int i = 0; i < 4; ++i) {
                int row = rowBase + rt*16 + quad*4 + i;
                int col = wave*64 + ct*16 + l16;
                V[(size_t)row*DD + col] = acc[rt][ct][i];
            }
    // reduce projection partials: tid = srow*8 + kt
    __syncthreads();
    pros[tid] = aq;
    pros[256 + tid] = ak;
    __syncthreads();
    if (tid < 32) {
        float sa = 0.f, sc = 0.f;
        #pragma unroll
        for (int j = 0; j < 8; ++j) {
            sa += pros[tid*8 + j];
            sc += pros[256 + tid*8 + j];
        }
        a[rowBase + tid] = sa + bmlp[0];
        c[rowBase + tid] = sc;
    }
}

// ---------------- K3: counting sort by value-bin + SE prefix ----------------
__global__ void __launch_bounds__(1024) k_sortish(const float* __restrict__ c,
        int* __restrict__ binstart_g, int* __restrict__ perm,
        float* __restrict__ c_sorted, float* __restrict__ e_sorted,
        float* __restrict__ SE, float* __restrict__ hdr) {
    __shared__ float cl[LL];
    __shared__ int   hist[NB];
    __shared__ float esl[LL];
    __shared__ float scrf[64];
    int b = blockIdx.x, tid = threadIdx.x;
    int wave = tid >> 6, lane = tid & 63;
    int* scri = (int*)scrf;

    float4 cv = ((const float4*)(c + (size_t)b*LL))[tid];
    ((float4*)cl)[tid] = cv;
    float cw[4] = {cv.x, cv.y, cv.z, cv.w};
    float mn = fminf(fminf(cw[0],cw[1]), fminf(cw[2],cw[3]));
    float mx = fmaxf(fmaxf(cw[0],cw[1]), fmaxf(cw[2],cw[3]));
    #pragma unroll
    for (int off = 32; off > 0; off >>= 1) {
        mn = fminf(mn, __shfl_down(mn, off));
        mx = fmaxf(mx, __shfl_down(mx, off));
    }
    if (lane == 0) { scrf[wave] = mn; scrf[32 + wave] = mx; }
    __syncthreads();
    if (wave == 0) {
        float m = (lane < 16) ? scrf[lane]      :  3.4e38f;
        float M = (lane < 16) ? scrf[32 + lane] : -3.4e38f;
        #pragma unroll
        for (int off = 32; off > 0; off >>= 1) {
            m = fminf(m, __shfl_down(m, off));
            M = fmaxf(M, __shfl_down(M, off));
        }
        if (lane == 0) { scrf[0] = m; scrf[1] = M; }
    }
    __syncthreads();
    float cmin = scrf[0], cmax = scrf[1];
    float scale = (float)NB / fmaxf(cmax - cmin, 1e-20f);
    __syncthreads();

    ((int4*)hist)[tid] = make_int4(0,0,0,0);
    ((int4*)hist)[tid + 1024] = make_int4(0,0,0,0);
    __syncthreads();

    int bins[4];
    #pragma unroll
    for (int u = 0; u < 4; ++u) {
        int bi = (int)((cw[u] - cmin) * scale);
        bi = bi < 0 ? 0 : (bi > NB-1 ? NB-1 : bi);
        bins[u] = bi;
        atomicAdd(&hist[bi], 1);
    }
    __syncthreads();

    int loc[8]; int base = 0;
    #pragma unroll
    for (int j = 0; j < 8; ++j) { loc[j] = base; base += hist[tid*8 + j]; }
    int incl = base;
    #pragma unroll
    for (int off = 1; off < 64; off <<= 1) {
        int t = __shfl_up(incl, off);
        if (lane >= off) incl += t;
    }
    if (lane == 63) scri[wave] = incl;
    __syncthreads();
    if (wave == 0) {
        int v = (lane < 16) ? scri[lane] : 0;
        int s = v;
        #pragma unroll
        for (int off = 1; off < 16; off <<= 1) {
            int t = __shfl_up(s, off);
            if (lane >= off) s += t;
        }
        if (lane < 16) scri[lane] = s - v;
    }
    __syncthreads();
    int thread_excl = (incl - base) + scri[wave];
    __syncthreads();
    #pragma unroll
    for (int j = 0; j < 8; ++j) {
        int bs = thread_excl + loc[j];
        binstart_g[(size_t)b*(NB+2) + tid*8 + j] = bs;
        hist[tid*8 + j] = bs;
    }
    if (tid == 0) {
        binstart_g[(size_t)b*(NB+2) + NB]     = LL;
        binstart_g[(size_t)b*(NB+2) + NB + 1] = LL;
        hdr[b*2 + 0] = cmin;
        hdr[b*2 + 1] = scale;
    }
    __syncthreads();

    #pragma unroll
    for (int u = 0; u < 4; ++u) {
        int i = tid*4 + u;
        int r = atomicAdd(&hist[bins[u]], 1);
        float e = expf(cmin - cw[u]);
        perm[(size_t)b*LL + r] = i;
        c_sorted[(size_t)b*LL + r] = cw[u];
        e_sorted[(size_t)b*LL + r] = e;
        esl[r] = e;
    }
    __syncthreads();

    float le[4]; float s0 = 0.f;
    #pragma unroll
    for (int u = 0; u < 4; ++u) { le[u] = s0; s0 += esl[tid*4 + u]; }
    float fincl = s0;
    #pragma unroll
    for (int off = 1; off < 64; off <<= 1) {
        float t = __shfl_up(fincl, off);
        if (lane >= off) fincl += t;
    }
    if (lane == 63) scrf[wave] = fincl;
    __syncthreads();
    if (wave == 0) {
        float v = (lane < 16) ? scrf[lane] : 0.f;
        float s = v;
        #pragma unroll
        for (int off = 1; off < 16; off <<= 1) {
            float t = __shfl_up(s, off);
            if (lane >= off) s += t;
        }
        if (lane < 16) scrf[lane] = s - v;
    }
    __syncthreads();
    float texcl = (fincl - s0) + scrf[wave];
    #pragma unroll
    for (int u = 0; u < 4; ++u)
        SE[(size_t)b*(LL+1) + tid*4 + u] = texcl + le[u];
    if (tid == 1023) SE[(size_t)b*(LL+1) + LL] = texcl + s0;
}

// ---------------- K4: chunked exclusive prefix over V in rank order ----------------
__global__ void k_scan(const float* __restrict__ V, const int* __restrict__ perm,
        const float* __restrict__ e_sorted,
        float* __restrict__ Pl, float* __restrict__ Pel,
        float* __restrict__ Tp, float* __restrict__ Te) {
    int b = blockIdx.y, q = blockIdx.x;
    int d = threadIdx.x;
    __shared__ int pj[CHUNK];
    __shared__ float pe[CHUNK];
    if (d < CHUNK) {
        pj[d] = perm[(size_t)b*LL + q*CHUNK + d];
        pe[d] = e_sorted[(size_t)b*LL + q*CHUNK + d];
    }
    __syncthreads();
    float vr[CHUNK];
    #pragma unroll
    for (int r = 0; r < CHUNK; ++r)
        vr[r] = V[((size_t)b*LL + pj[r]) * DD + d];
    float acc = 0.f, acce = 0.f;
    size_t kb = (size_t)b*LL + (size_t)q*CHUNK;
    #pragma unroll
    for (int r = 0; r < CHUNK; ++r) {
        size_t o = (kb + r) * DD + d;
        Pl[o]  = acc;
        Pel[o] = acce;
        acc += vr[r];
        acce = fmaf(pe[r], vr[r], acce);
    }
    size_t to = ((size_t)b*NC + q) * DD + d;
    Tp[to] = acc;
    Te[to] = acce;
}

// ---------------- K5: chunk bases, parallel over (q, b) ----------------
// block (q, b): baseP[b][q][:] = sum_{i<q} Tp[b][i][:]  (q in [0, NC])
__global__ void k_base(const float* __restrict__ Tp, const float* __restrict__ Te,
        float* __restrict__ baseP, float* __restrict__ basePe) {
    int q = blockIdx.x, b = blockIdx.y, d = threadIdx.x;
    float acc = 0.f, acce = 0.f;
    #pragma unroll 8
    for (int i = 0; i < q; ++i) {
        size_t ti = ((size_t)b*NC + i) * DD + d;
        acc += Tp[ti]; acce += Te[ti];
    }
    size_t o = ((size_t)b*(NC+1) + q) * DD + d;
    baseP[o] = acc; basePe[o] = acce;
}

// ---------------- K6: per-row output, O(1) bin lookup + exact boundary fix ----------------
__global__ void k_out(const float* __restrict__ a, const float* __restrict__ hdr,
                      const int* __restrict__ binstart,
                      const float* __restrict__ c_sorted, const float* __restrict__ e_sorted,
                      const int* __restrict__ perm, const float* __restrict__ V,
                      const float* __restrict__ SE,
                      const float* __restrict__ Pl, const float* __restrict__ Pel,
                      const float* __restrict__ baseP, const float* __restrict__ basePe,
                      float* __restrict__ out) {
    int row = blockIdx.x * 4 + (threadIdx.x >> 6);
    int lane = threadIdx.x & 63;
    int b = row >> 12;
    float ai = a[row];
    float cmin = hdr[b*2 + 0], scale = hdr[b*2 + 1];
    float t = (ai - cmin) * scale;
    int ib = t < 0.f ? 0 : (t >= (float)NB ? NB : (int)t);
    int k    = binstart[(size_t)b*(NB+2) + ib];
    int kend = binstart[(size_t)b*(NB+2) + ib + 1];
    float alpha = expf(cmin - ai);
    float Z = fmaf(alpha, (float)(LL - k), SE[(size_t)b*(LL+1) + k]);
    size_t db = (size_t)lane * 4;
    size_t totoff = ((size_t)b * (NC+1) + NC) * DD + db;
    float4 ptot  = *(const float4*)(baseP  + totoff);
    float4 pk, pek;
    if (k < LL) {
        int q = k >> 5;
        size_t po = ((size_t)b * LL + k) * DD + db;
        size_t bo = ((size_t)b * (NC+1) + q) * DD + db;
        float4 pl = *(const float4*)(Pl    + po);
        float4 bp = *(const float4*)(baseP + bo);
        float4 pe = *(const float4*)(Pel    + po);
        float4 be = *(const float4*)(basePe + bo);
        pk.x = pl.x + bp.x; pk.y = pl.y + bp.y; pk.z = pl.z + bp.z; pk.w = pl.w + bp.w;
        pek.x = pe.x + be.x; pek.y = pe.y + be.y; pek.z = pe.z + be.z; pek.w = pe.w + be.w;
    } else {
        pk = ptot;
        float4 pt = *(const float4*)(basePe + totoff);
        pek = pt;
    }
    float4 num;
    num.x = fmaf(alpha, ptot.x - pk.x, pek.x);
    num.y = fmaf(alpha, ptot.y - pk.y, pek.y);
    num.z = fmaf(alpha, ptot.z - pk.z, pek.z);
    num.w = fmaf(alpha, ptot.w - pk.w, pek.w);
    for (int r = k; r < kend; ++r) {
        float cr = c_sorted[(size_t)b*LL + r];
        if (cr < ai) {
            float w = e_sorted[(size_t)b*LL + r] - alpha;
            int j = perm[(size_t)b*LL + r];
            float4 v = *(const float4*)(V + ((size_t)b*LL + j) * DD + db);
            num.x = fmaf(w, v.x, num.x);
            num.y = fmaf(w, v.y, num.y);
            num.z = fmaf(w, v.z, num.z);
            num.w = fmaf(w, v.w, num.w);
            Z += w;
        }
    }
    float invZ = 1.f / Z;
    float4 o;
    o.x = num.x * invZ; o.y = num.y * invZ; o.z = num.z * invZ; o.w = num.w * invZ;
    *(float4*)(out + (size_t)row * DD + db) = o;
}

extern "C" void kernel_launch(void* const* d_in, const int* in_sizes, int n_in,
                              void* d_out, int out_size, void* d_ws, size_t ws_size,
                              hipStream_t stream) {
    const float* x  = (const float*)d_in[0];
    const float* Wq = (const float*)d_in[1];
    const float* Wk = (const float*)d_in[2];
    const float* Wv = (const float*)d_in[3];
    const float* wm = (const float*)d_in[4];
    const float* bm = (const float*)d_in[5];
    float* out = (float*)d_out;
    float* ws = (float*)d_ws;

    size_t off = 0;
    auto alloc = [&](size_t n) {      // n in floats
        float* p = ws + off;
        off += (n + 255) & ~(size_t)255;
        return p;
    };
    float* u        = alloc(2*DD);
    float* a        = alloc(NROWS);
    float* c        = alloc(NROWS);
    float* c_sorted = alloc(NROWS);
    float* e_sorted = alloc(NROWS);
    float* SE       = alloc((size_t)BB*(LL+1));
    int*   perm     = (int*)alloc(NROWS);
    int*   binstart = (int*)alloc((size_t)BB*(NB+2));
    float* hdr      = alloc(2*BB);
    float* V        = alloc((size_t)NROWS*DD);
    float* Pl       = alloc((size_t)NROWS*DD);
    float* Pel      = alloc((size_t)NROWS*DD);
    float* Tp       = alloc((size_t)BB*NC*DD);
    float* Te       = alloc((size_t)BB*NC*DD);
    float* baseP    = alloc((size_t)BB*(NC+1)*DD);
    float* basePe   = alloc((size_t)BB*(NC+1)*DD);
    __bf16* Wh      = (__bf16*)alloc((size_t)DD*DD/2);
    __bf16* Wl      = (__bf16*)alloc((size_t)DD*DD/2);

    hipMemsetAsync(u, 0, 2*DD*sizeof(float), stream);
    hipLaunchKernelGGL(k_prep, dim3(16), dim3(DD), 0, stream, Wq, Wk, Wv, wm, u, Wh, Wl);
    hipLaunchKernelGGL(k_gemm_mfma, dim3(NROWS/32), dim3(256), 0, stream,
                       x, Wh, Wl, u, bm, V, a, c);
    hipLaunchKernelGGL(k_sortish, dim3(BB), dim3(1024), 0, stream,
                       c, binstart, perm, c_sorted, e_sorted, SE, hdr);
    hipLaunchKernelGGL(k_scan, dim3(NC, BB), dim3(DD), 0, stream, V, perm, e_sorted, Pl, Pel, Tp, Te);
    hipLaunchKernelGGL(k_base, dim3(NC+1, BB), dim3(DD), 0, stream, Tp, Te, baseP, basePe);
    hipLaunchKernelGGL(k_out, dim3(NROWS/4), dim3(256), 0, stream,
                       a, hdr, binstart, c_sorted, e_sorted, perm, V,
                       SE, Pl, Pel, baseP, basePe, out);
}